// Round 2
// baseline (550.996 us; speedup 1.0000x reference)
//
#include <hip/hip_runtime.h>
#include <hip/hip_bf16.h>

#define EMB 768
#define HD 1024
#define D3 128
#define CTXN 512
#define BB 8
#define SS 64

typedef __attribute__((ext_vector_type(8))) short short8v;
typedef __attribute__((ext_vector_type(4))) float f32x4;

__device__ __forceinline__ float fast_tanh(float x) {
  float e = __expf(2.f * x);
  return 1.f - 2.f * __builtin_amdgcn_rcpf(e + 1.f);
}
__device__ __forceinline__ float bf2f(__hip_bfloat16 x) { return __bfloat162float(x); }

// ---------------- kcast: Maug1=[W_s;b_s] bf16, W1T = W_s^T bf16, Gmat[0:8] = h0 bf16
__global__ __launch_bounds__(256) void kcast(const float* __restrict__ W_s,
                                             const float* __restrict__ b_s,
                                             const float* __restrict__ context,
                                             __hip_bfloat16* __restrict__ Maug1,
                                             __hip_bfloat16* __restrict__ W1T,
                                             __hip_bfloat16* __restrict__ Gmat) {
  int blk = blockIdx.x, tid = threadIdx.x;
  int r0 = (blk >> 4) * 64, c0 = (blk & 15) * 64;
  __shared__ __hip_bfloat16 t[64][65];
  for (int i = tid; i < 64 * 64; i += 256) {
    int r = i >> 6, c = i & 63;
    __hip_bfloat16 bv = __float2bfloat16(W_s[(long)(r0 + r) * HD + c0 + c]);
    Maug1[(long)(r0 + r) * HD + c0 + c] = bv;
    t[r][c] = bv;
  }
  __syncthreads();
  for (int i = tid; i < 64 * 64; i += 256) {
    int c = i >> 6, r = i & 63;
    W1T[(long)(c0 + c) * HD + r0 + r] = t[r][c];
  }
  if (blk == 0) {
    for (int i = tid; i < HD; i += 256)
      Maug1[(long)HD * HD + i] = __float2bfloat16(b_s[i]);
    for (int i = tid; i < BB * HD; i += 256) {
      int b = i >> 10, k = i & 1023;
      Gmat[i] = __float2bfloat16(context[((long)b * CTXN + (CTXN - 1)) * HD + k]);
    }
  }
}

// ---------------- gemm16: C[M,N] = A[M,K]@B[K,N] (+bias_f row-bcast)(+addrow to row M-1)
// outputs: Cf fp32, Cb bf16, CbT bf16 transposed (stride HD, rows<HD only)
template <bool AF32, bool BF32>
__global__ __launch_bounds__(256) void gemm16(const void* __restrict__ Ap, int lda, int M,
                                              const void* __restrict__ Bp, int ldb, int N,
                                              int K,
                                              const __hip_bfloat16* __restrict__ addrow,
                                              const float* __restrict__ bias_f,
                                              float* __restrict__ Cf,
                                              __hip_bfloat16* __restrict__ Cb,
                                              __hip_bfloat16* __restrict__ CbT) {
  const float* Af = (const float*)Ap;
  const __hip_bfloat16* Ab = (const __hip_bfloat16*)Ap;
  const float* Bf = (const float*)Bp;
  const __hip_bfloat16* Bb = (const __hip_bfloat16*)Bp;
  __shared__ __hip_bfloat16 As[64][40];  // padded: 80B rows -> 2-way-max conflicts
  __shared__ __hip_bfloat16 Bt[64][40];  // transposed B tile [n][k]
  int tid = threadIdx.x;
  int lane = tid & 63, wid = tid >> 6;
  int l16 = lane & 15, g = lane >> 4;
  int bm0 = blockIdx.x * 64, bn0 = blockIdx.y * 64;
  int wm = (wid >> 1) * 32, wn = (wid & 1) * 32;
  f32x4 acc[2][2] = {};
  int arow = tid >> 2, aseg = tid & 3;
  int brow = tid >> 3, bseg = tid & 7;
  for (int k0 = 0; k0 < K; k0 += 32) {
    __syncthreads();
    {  // stage A [64 x 32]
      int gr = bm0 + arow;
      __hip_bfloat16 tmp[8];
      if (gr < M) {
        if (AF32) {
          const float* src = &Af[(long)gr * lda + k0 + aseg * 8];
#pragma unroll
          for (int j = 0; j < 8; ++j) tmp[j] = __float2bfloat16(src[j]);
        } else {
          *(short8v*)tmp = *(const short8v*)&Ab[(long)gr * lda + k0 + aseg * 8];
        }
      } else {
#pragma unroll
        for (int j = 0; j < 8; ++j) tmp[j] = __float2bfloat16(0.f);
      }
      *(short8v*)&As[arow][aseg * 8] = *(short8v*)tmp;
    }
    {  // stage B [32 x 64] transposed into Bt
      int gk = k0 + brow;
      __hip_bfloat16 tv[8];
      if (BF32) {
        const float* src = &Bf[(long)gk * ldb + bn0 + bseg * 8];
#pragma unroll
        for (int j = 0; j < 8; ++j) tv[j] = __float2bfloat16(src[j]);
      } else {
        *(short8v*)tv = *(const short8v*)&Bb[(long)gk * ldb + bn0 + bseg * 8];
      }
#pragma unroll
      for (int j = 0; j < 8; ++j) Bt[bseg * 8 + j][brow] = tv[j];
    }
    __syncthreads();
    short8v a0 = *(const short8v*)&As[wm + l16][g * 8];
    short8v a1 = *(const short8v*)&As[wm + 16 + l16][g * 8];
    short8v b0 = *(const short8v*)&Bt[wn + l16][g * 8];
    short8v b1 = *(const short8v*)&Bt[wn + 16 + l16][g * 8];
    acc[0][0] = __builtin_amdgcn_mfma_f32_16x16x32_bf16(a0, b0, acc[0][0], 0, 0, 0);
    acc[0][1] = __builtin_amdgcn_mfma_f32_16x16x32_bf16(a0, b1, acc[0][1], 0, 0, 0);
    acc[1][0] = __builtin_amdgcn_mfma_f32_16x16x32_bf16(a1, b0, acc[1][0], 0, 0, 0);
    acc[1][1] = __builtin_amdgcn_mfma_f32_16x16x32_bf16(a1, b1, acc[1][1], 0, 0, 0);
  }
#pragma unroll
  for (int i = 0; i < 2; ++i)
#pragma unroll
    for (int j = 0; j < 2; ++j)
#pragma unroll
      for (int r = 0; r < 4; ++r) {
        int grow = bm0 + wm + i * 16 + g * 4 + r;
        int gcol = bn0 + wn + j * 16 + l16;
        if (grow < M && gcol < N) {
          float v = acc[i][j][r];
          if (bias_f) v += bias_f[gcol];
          if (addrow && grow == M - 1) v += bf2f(addrow[gcol]);
          if (Cf) Cf[(long)grow * N + gcol] = v;
          if (Cb) Cb[(long)grow * N + gcol] = __float2bfloat16(v);
          if (CbT && grow < HD) CbT[(long)gcol * HD + grow] = __float2bfloat16(v);
        }
      }
}

// ---------------- smgemm: small-M GEMM, no LDS, B pre-transposed BT[N=1024][K=1024]
// C[M,1024] = A[M,1024]@B + bias ; Cf fp32 (optional h_all scatter), Cb bf16
template <int MT>
__global__ __launch_bounds__(256) void smgemm(const __hip_bfloat16* __restrict__ A, int M,
                                              const __hip_bfloat16* __restrict__ BT,
                                              const float* __restrict__ bias_f,
                                              const __hip_bfloat16* __restrict__ bias_bf,
                                              float* __restrict__ Cf, int cf_scatter,
                                              __hip_bfloat16* __restrict__ Cb) {
  int lane = threadIdx.x & 63, w = threadIdx.x >> 6;
  int n0 = blockIdx.x * 64 + w * 16;
  int l16 = lane & 15, g = lane >> 4;
  f32x4 acc[MT] = {};
  const long bbase = (long)(n0 + l16) * HD;
#pragma unroll 4
  for (int k0 = 0; k0 < HD; k0 += 32) {
    short8v bfr = *(const short8v*)&BT[bbase + k0 + g * 8];
#pragma unroll
    for (int i = 0; i < MT; ++i) {
      int row = i * 16 + l16;
      short8v afr = {};
      if (row < M) afr = *(const short8v*)&A[(long)row * HD + k0 + g * 8];
      acc[i] = __builtin_amdgcn_mfma_f32_16x16x32_bf16(afr, bfr, acc[i], 0, 0, 0);
    }
  }
#pragma unroll
  for (int i = 0; i < MT; ++i)
#pragma unroll
    for (int r = 0; r < 4; ++r) {
      int grow = i * 16 + g * 4 + r;
      if (grow < M) {
        int gcol = n0 + l16;
        float v = acc[i][r];
        if (bias_f) v += bias_f[gcol];
        if (bias_bf) v += bf2f(bias_bf[gcol]);
        if (Cf) {
          long off = cf_scatter ? ((long)(grow >> 3) * (8L * BB * HD) + (long)(grow & 7) * HD + gcol)
                                : ((long)grow * HD + gcol);
          Cf[off] = v;
        }
        if (Cb) Cb[(long)grow * HD + gcol] = __float2bfloat16(v);
      }
    }
}

// ---------------- kpre: Wc = W_in @ W_att_in[:1024], qb = b_in@Wa_top + b_att_in
__global__ __launch_bounds__(256) void kpre(const float* __restrict__ W_in,
                                            const float* __restrict__ b_in,
                                            const float* __restrict__ W_att_in,
                                            const float* __restrict__ b_att_in,
                                            float* __restrict__ Wc,
                                            float* __restrict__ qb) {
  int blk = blockIdx.x;
  int tid = threadIdx.x;
  if (blk == 96) {
    if (tid < 128) {
      int d = tid;
      float acc = b_att_in[d];
      for (int k = 0; k < HD; ++k) acc += b_in[k] * W_att_in[k * D3 + d];
      qb[d] = acc;
    }
    return;
  }
  int r0 = blk * 8;
  int d = tid & 127, rh = tid >> 7;
  __shared__ float lw[8][128];
  float acc[4] = {0.f, 0.f, 0.f, 0.f};
  for (int kc = 0; kc < 8; ++kc) {
    __syncthreads();
    for (int i = tid; i < 8 * 128; i += 256) {
      int r = i >> 7, k = i & 127;
      lw[r][k] = W_in[(r0 + r) * HD + kc * 128 + k];
    }
    __syncthreads();
    for (int k = 0; k < 128; ++k) {
      float w = W_att_in[(kc * 128 + k) * D3 + d];
#pragma unroll
      for (int r = 0; r < 4; ++r) acc[r] = fmaf(lw[rh * 4 + r][k], w, acc[r]);
    }
  }
#pragma unroll
  for (int r = 0; r < 4; ++r) Wc[(r0 + rh * 4 + r) * D3 + d] = acc[r];
}

// ---------------- kqf: q[t][b][d] = feats@Wc + h_t@W_att_in[1024:] + qb
__global__ __launch_bounds__(256) void kqf(const int* __restrict__ ids,
                                           const float* __restrict__ emb,
                                           const float* __restrict__ Wc,
                                           const float* __restrict__ W_att_in,
                                           const float* __restrict__ qb,
                                           const float* __restrict__ h_all,
                                           float* __restrict__ q) {
  int blk = blockIdx.x;
  int b = blk >> 5, tp = blk & 31;
  int tid = threadIdx.x;
  __shared__ float lf[2][768];
  __shared__ float lh[2][1024];
  __shared__ float red[2][2][128];
  for (int u = 0; u < 2; ++u) {
    int t = tp * 2 + u;
    int id = ids[b * SS + t];
    for (int i = tid; i < EMB; i += 256) lf[u][i] = emb[(long)id * EMB + i];
    for (int i = tid; i < HD; i += 256) lh[u][i] = h_all[((long)t * BB + b) * HD + i];
  }
  __syncthreads();
  int d = tid & 127, kh = tid >> 7;
  float acc0 = 0.f, acc1 = 0.f;
  for (int k = kh * 384; k < kh * 384 + 384; ++k) {
    float w = Wc[k * D3 + d];
    acc0 = fmaf(lf[0][k], w, acc0);
    acc1 = fmaf(lf[1][k], w, acc1);
  }
  for (int k = kh * 512; k < kh * 512 + 512; ++k) {
    float w = W_att_in[(HD + k) * D3 + d];
    acc0 = fmaf(lh[0][k], w, acc0);
    acc1 = fmaf(lh[1][k], w, acc1);
  }
  red[0][kh][d] = acc0;
  red[1][kh][d] = acc1;
  __syncthreads();
  if (kh == 0) {
    float base = qb[d];
    int t = tp * 2;
    q[((t)*BB + b) * D3 + d] = red[0][0][d] + red[0][1][d] + base;
    q[((t + 1) * BB + b) * D3 + d] = red[1][0][d] + red[1][1][d] + base;
  }
}

// ---------------- katt: out[b][t][c] = sum_d V[d]*tanh(q[t][b][d] + ctxp[b][c][d])
__global__ __launch_bounds__(256) void katt(const float* __restrict__ q,
                                            const float* __restrict__ ctxp,
                                            const float* __restrict__ V,
                                            float* __restrict__ out) {
  int blk = blockIdx.x;
  int b = blk >> 5, tt = (blk >> 4) & 1, ct = blk & 15;
  int t0 = tt * 32, c0 = ct * 32;
  int tid = threadIdx.x;
  __shared__ float lq[32][128];
  __shared__ float lc[32][132];
  __shared__ float lv[128];
  for (int i = tid; i < 32 * 128; i += 256) {
    int r = i >> 7, d = i & 127;
    lq[r][d] = q[((long)(t0 + r) * BB + b) * D3 + d];
    lc[r][d] = ctxp[((long)b * CTXN + c0 + r) * D3 + d];
  }
  if (tid < 128) lv[tid] = V[tid];
  __syncthreads();
  int cl = tid & 31, tg = tid >> 5;
  float r[4] = {0.f, 0.f, 0.f, 0.f};
  for (int d4 = 0; d4 < 32; ++d4) {
    float4 cv = *reinterpret_cast<const float4*>(&lc[cl][d4 * 4]);
    float4 vv = *reinterpret_cast<const float4*>(&lv[d4 * 4]);
#pragma unroll
    for (int u = 0; u < 4; ++u) {
      int t = tg + u * 8;
      float4 qv = *reinterpret_cast<const float4*>(&lq[t][d4 * 4]);
      r[u] = fmaf(vv.x, fast_tanh(qv.x + cv.x), r[u]);
      r[u] = fmaf(vv.y, fast_tanh(qv.y + cv.y), r[u]);
      r[u] = fmaf(vv.z, fast_tanh(qv.z + cv.z), r[u]);
      r[u] = fmaf(vv.w, fast_tanh(qv.w + cv.w), r[u]);
    }
  }
#pragma unroll
  for (int u = 0; u < 4; ++u) {
    int t = tg + u * 8;
    out[((long)b * SS + (t0 + t)) * CTXN + c0 + cl] = r[u];
  }
  if (blk == 0) {
    for (int i = tid; i < SS * BB; i += 256) out[(long)BB * SS * CTXN + i] = 0.f;
  }
}

extern "C" void kernel_launch(void* const* d_in, const int* in_sizes, int n_in,
                              void* d_out, int out_size, void* d_ws, size_t ws_size,
                              hipStream_t stream) {
  const int* ids = (const int*)d_in[0];
  const float* context = (const float*)d_in[4];
  const float* emb = (const float*)d_in[5];
  const float* W_in = (const float*)d_in[6];
  const float* b_in = (const float*)d_in[7];
  const float* W_s = (const float*)d_in[8];
  const float* b_s = (const float*)d_in[9];
  const float* W_att_in = (const float*)d_in[10];
  const float* b_att_in = (const float*)d_in[11];
  const float* W_att_h = (const float*)d_in[12];
  const float* b_att_h = (const float*)d_in[13];
  const float* V = (const float*)d_in[14];

  float* ws = (float*)d_ws;
  float* Wc = ws;                  // 98304
  float* qb = Wc + 98304;          // 128
  float* q = qb + 128;             // 65536
  float* ctxp = q + 65536;         // 524288
  float* h_all = ctxp + 524288;    // 524288
  __hip_bfloat16* bfp = (__hip_bfloat16*)(h_all + 524288);
  __hip_bfloat16* MaugA = bfp;                      // 1025*1024
  __hip_bfloat16* MaugB = MaugA + 1025 * 1024;      // 1025*1024
  __hip_bfloat16* W1T = MaugB + 1025 * 1024;        // 1024*1024
  __hip_bfloat16* W8T = W1T + 1024 * 1024;          // 1024*1024
  __hip_bfloat16* Gmat = W8T + 1024 * 1024;         // 64*1024
  __hip_bfloat16* Hbuf = Gmat + 64 * 1024;          // 2*64*1024
  float* out = (float*)d_out;

  kcast<<<dim3(256), dim3(256), 0, stream>>>(W_s, b_s, context, MaugA, W1T, Gmat);
  kpre<<<dim3(97), dim3(256), 0, stream>>>(W_in, b_in, W_att_in, b_att_in, Wc, qb);
  // ctx_proj via MFMA (fp32 inputs, staged to bf16)
  gemm16<true, true><<<dim3(64, 2), dim3(256), 0, stream>>>(
      context, HD, 4096, W_att_h, D3, D3, HD, nullptr, b_att_h, ctxp, nullptr, nullptr);
  // affine squarings: A^2, A^4, A^8  (augmented [W;b], addrow composes bias)
  gemm16<false, false><<<dim3(17, 16), dim3(256), 0, stream>>>(
      MaugA, HD, 1025, MaugA, HD, HD, HD, MaugA + (long)HD * HD, nullptr, nullptr, MaugB, nullptr);
  gemm16<false, false><<<dim3(17, 16), dim3(256), 0, stream>>>(
      MaugB, HD, 1025, MaugB, HD, HD, HD, MaugB + (long)HD * HD, nullptr, nullptr, MaugA, nullptr);
  gemm16<false, false><<<dim3(17, 16), dim3(256), 0, stream>>>(
      MaugA, HD, 1025, MaugA, HD, HD, HD, MaugA + (long)HD * HD, nullptr, nullptr, MaugB, W8T);
  const __hip_bfloat16* b8 = MaugB + (long)HD * HD;
  // checkpoints: g_{k+1} = g_k @ W8 + b8 ; h_all[8k+7] = g_{k+1}
  for (int k = 0; k < 8; ++k) {
    smgemm<1><<<dim3(16), dim3(256), 0, stream>>>(
        Gmat + (long)k * BB * HD, 8, W8T, nullptr, b8,
        h_all + (long)(8 * k + 7) * BB * HD, 0,
        (k < 7) ? (Gmat + (long)(k + 1) * BB * HD) : nullptr);
  }
  // fill: H_r = H_{r-1} @ W + b_s ; scatter rows (k,b) -> h_all[8k + r - 1]
  for (int r = 1; r <= 7; ++r) {
    const __hip_bfloat16* Aprev = (r == 1) ? Gmat : (Hbuf + (long)((r - 1) & 1) * 64 * HD);
    smgemm<4><<<dim3(16), dim3(256), 0, stream>>>(
        Aprev, 64, W1T, b_s, nullptr, h_all + (long)(r - 1) * BB * HD, 1,
        (r < 7) ? (Hbuf + (long)(r & 1) * 64 * HD) : nullptr);
  }
  kqf<<<dim3(256), dim3(256), 0, stream>>>(ids, emb, Wc, W_att_in, qb, h_all, q);
  katt<<<dim3(256), dim3(256), 0, stream>>>(q, ctxp, V, out);
}